// Round 1
// 1330.447 us; speedup vs baseline: 1.1165x; 1.1165x over previous
//
#include <hip/hip_runtime.h>
#include <math.h>

// Problem constants (fixed by setup_inputs)
#define BB    32
#define HQ    32
#define HKV   8
#define DD    128
#define PAGE  16
#define GRP   4    // HQ / HKV
#define SPLIT 8    // flash-decode splits per sequence
#define PSTR  130  // floats per partial record: o[128], m, l

// Async global->LDS DMA, 16 B per lane. LDS dest is wave-uniform base + lane*16.
__device__ __forceinline__ void async_ld16(const float* g, float* l) {
    __builtin_amdgcn_global_load_lds(
        (__attribute__((address_space(1))) void*)(g),
        (__attribute__((address_space(3))) void*)(l),
        16, 0, 0);
}

// One block per (b, kv_head, split). 256 threads = 4 waves; wave w handles
// query head h*4+w. Each block processes pages [j0, j1) of sequence b and
// writes an UNNORMALIZED partial (o, m, l) to the workspace.
__global__ __launch_bounds__(256) void paged_decode_split(
    const float* __restrict__ q,        // [B, HQ, 1, D]
    const float* __restrict__ kv,       // [NPAGES, 2, HKV, PAGE, D]
    const int*  __restrict__ indptr,    // [B+1]
    const int*  __restrict__ indices,   // [NPAGES]
    const int*  __restrict__ lastlen,   // [B]
    float* __restrict__ ws)             // [B*HQ, SPLIT, PSTR]
{
    __shared__ __align__(16) float sK[2][PAGE * DD];   // 2 x 8 KiB
    __shared__ __align__(16) float sV[2][PAGE * DD];   // 2 x 8 KiB

    const int tid  = threadIdx.x;
    const int w    = tid >> 6;     // wave id 0..3
    const int lane = tid & 63;
    const int r    = lane >> 2;    // row 0..15
    const int sub  = lane & 3;     // 4 lanes per row

    const int sp = blockIdx.x & 7;         // split 0..7
    const int h  = (blockIdx.x >> 3) & 7;  // kv head
    const int b  = blockIdx.x >> 6;        // batch
    const int qh = h * GRP + w;

    // q fragment, column-rotated by 4*r so LDS K reads are bank-conflict-free:
    // lane covers columns {(sub*32 + 4r + 4i) mod 128 .. +3}, i = 0..7
    const float* qb = q + (size_t)(b * HQ + qh) * DD;
    float4 qv[8];
#pragma unroll
    for (int i = 0; i < 8; ++i) {
        int c = (sub * 32 + 4 * r + 4 * i) & 127;
        qv[i] = *(const float4*)(qb + c);
    }

    const int start = indptr[b];
    const int np    = indptr[b + 1] - start;   // 256 here
    const int ll    = lastlen[b];
    const int npp   = (np + SPLIT - 1) / SPLIT;
    const int j0    = sp * npp;
    const int j1    = (j0 + npp < np) ? (j0 + npp) : np;

    float* P = ws + ((size_t)(b * HQ + qh) * SPLIT + sp) * PSTR;

    if (j0 >= j1) {   // empty split (not reachable for np=256, kept for safety)
        float2 z; z.x = 0.0f; z.y = 0.0f;
        *(float2*)(P + 2 * lane) = z;
        if (lane == 0) { P[128] = -INFINITY; P[129] = 0.0f; }
        return;
    }

    // Prefetch first page of this split into buffer 0.
    {
        const int pid0 = indices[start + j0];
        const float* base = kv + (size_t)pid0 * (2 * HKV * PAGE * DD) + h * (PAGE * DD);
        const int c0 = w * 2;  // chunk index (256 floats per chunk)
        async_ld16(base + c0 * 256 + lane * 4,                 &sK[0][c0 * 256]);
        async_ld16(base + c0 * 256 + 256 + lane * 4,           &sK[0][c0 * 256 + 256]);
        async_ld16(base + HKV * PAGE * DD + c0 * 256 + lane * 4,       &sV[0][c0 * 256]);
        async_ld16(base + HKV * PAGE * DD + c0 * 256 + 256 + lane * 4, &sV[0][c0 * 256 + 256]);
    }
    int pid_next = (j0 + 1 < j1) ? indices[start + j0 + 1] : 0;

    float m = -INFINITY;
    float l = 0.0f;
    float ox = 0.0f, oy = 0.0f;
    const float scale = 0.08838834764831845f;  // 1/sqrt(128)

    for (int j = j0; j < j1; ++j) {
        __syncthreads();   // drains DMA for current buffer (and fences LDS)
        const int buf = (j - j0) & 1;

        // Prefetch page j+1 into the other buffer; in flight during compute.
        if (j + 1 < j1) {
            const float* base = kv + (size_t)pid_next * (2 * HKV * PAGE * DD) + h * (PAGE * DD);
            const int c0 = w * 2;
            float* kb = &sK[buf ^ 1][0];
            float* vb = &sV[buf ^ 1][0];
            async_ld16(base + c0 * 256 + lane * 4,                 kb + c0 * 256);
            async_ld16(base + c0 * 256 + 256 + lane * 4,           kb + c0 * 256 + 256);
            async_ld16(base + HKV * PAGE * DD + c0 * 256 + lane * 4,       vb + c0 * 256);
            async_ld16(base + HKV * PAGE * DD + c0 * 256 + 256 + lane * 4, vb + c0 * 256 + 256);
        }
        pid_next = (j + 2 < j1) ? indices[start + j + 2] : 0;

        const float* Kb = sK[buf];
        const float* Vb = sV[buf];

        // Scores: lane does a 32-elem partial dot of K[r] with q (rotated cols).
        float acc = 0.0f;
#pragma unroll
        for (int i = 0; i < 8; ++i) {
            int c = (sub * 32 + 4 * r + 4 * i) & 127;
            float4 k4 = *(const float4*)(Kb + r * DD + c);
            acc += k4.x * qv[i].x + k4.y * qv[i].y + k4.z * qv[i].z + k4.w * qv[i].w;
        }
        acc += __shfl_xor(acc, 1, 64);
        acc += __shfl_xor(acc, 2, 64);
        float s = acc * scale;
        if ((j == np - 1) && (r >= ll)) s = -INFINITY;   // truncated last page

        // Page max over the 16 rows (values replicated across sub lanes).
        float pm = s;
        pm = fmaxf(pm, __shfl_xor(pm, 4, 64));
        pm = fmaxf(pm, __shfl_xor(pm, 8, 64));
        pm = fmaxf(pm, __shfl_xor(pm, 16, 64));
        pm = fmaxf(pm, __shfl_xor(pm, 32, 64));
        const float m_new = fmaxf(m, pm);
        const float p     = __expf(s - m_new);  // 0 for masked rows
        const float alpha = __expf(m - m_new);  // 0 on first page (m = -inf)
        m = m_new;

        float ps = p;
        ps += __shfl_xor(ps, 4, 64);
        ps += __shfl_xor(ps, 8, 64);
        ps += __shfl_xor(ps, 16, 64);
        ps += __shfl_xor(ps, 32, 64);
        l = l * alpha + ps;

        // O accumulation: lane owns columns {2*lane, 2*lane+1}.
        ox *= alpha; oy *= alpha;
        const float* vrow = Vb + lane * 2;
#pragma unroll
        for (int rr = 0; rr < 16; ++rr) {
            float pr = __shfl(p, rr * 4, 64);        // broadcast p[rr]
            float2 v2 = *(const float2*)(vrow + rr * DD);
            ox += pr * v2.x;
            oy += pr * v2.y;
        }
    }

    // Write unnormalized partial: o (lane owns 2 cols), then m, l (uniform).
    float2 res; res.x = ox; res.y = oy;
    *(float2*)(P + 2 * lane) = res;
    if (lane == 0) { P[128] = m; P[129] = l; }
}

// Combine: one wave per (b, qh). Max-rescaled merge of SPLIT partials.
__global__ __launch_bounds__(64) void paged_decode_combine(
    const float* __restrict__ ws,   // [B*HQ, SPLIT, PSTR]
    float* __restrict__ out)        // [B, HQ, 1, D]
{
    const int bh   = blockIdx.x;        // b*HQ + qh
    const int lane = threadIdx.x;       // 0..63, owns cols {2*lane, 2*lane+1}
    const float* P = ws + (size_t)bh * SPLIT * PSTR;

    float ms[SPLIT], ls[SPLIT];
    float M = -INFINITY;
#pragma unroll
    for (int s = 0; s < SPLIT; ++s) {
        ms[s] = P[s * PSTR + 128];
        ls[s] = P[s * PSTR + 129];
        M = fmaxf(M, ms[s]);
    }
    float L = 0.0f, ox = 0.0f, oy = 0.0f;
#pragma unroll
    for (int s = 0; s < SPLIT; ++s) {
        const float a = __expf(ms[s] - M);
        L += ls[s] * a;
        float2 o2 = *(const float2*)(P + s * PSTR + 2 * lane);
        ox += a * o2.x;
        oy += a * o2.y;
    }
    const float inv = 1.0f / L;
    float2 r; r.x = ox * inv; r.y = oy * inv;
    *(float2*)(out + (size_t)bh * DD + 2 * lane) = r;
}

extern "C" void kernel_launch(void* const* d_in, const int* in_sizes, int n_in,
                              void* d_out, int out_size, void* d_ws, size_t ws_size,
                              hipStream_t stream) {
    const float* q       = (const float*)d_in[0];
    const float* kv      = (const float*)d_in[1];
    const int*   indptr  = (const int*)d_in[2];
    const int*   indices = (const int*)d_in[3];
    const int*   lastlen = (const int*)d_in[4];
    float* out = (float*)d_out;
    float* ws  = (float*)d_ws;   // needs B*HQ*SPLIT*PSTR*4 = ~4.3 MB

    {
        dim3 grid(BB * HKV * SPLIT);   // 2048 blocks: (b, kv_head, split)
        dim3 block(256);               // 4 waves: one per query head in group
        hipLaunchKernelGGL(paged_decode_split, grid, block, 0, stream,
                           q, kv, indptr, indices, lastlen, ws);
    }
    {
        dim3 grid(BB * HQ);            // 1024 blocks: one per (b, qh)
        dim3 block(64);                // 1 wave
        hipLaunchKernelGGL(paged_decode_combine, grid, block, 0, stream,
                           ws, out);
    }
}